// Round 16
// baseline (135.190 us; speedup 1.0000x reference)
//
#include <hip/hip_runtime.h>
#include <hip/hip_bf16.h>

typedef __attribute__((ext_vector_type(8))) short bf16x8;
typedef __attribute__((ext_vector_type(4))) float f32x4;

#define NB 16
#define CD 256
#define HD 64
#define WD 64
#define WP 68   // padded width
#define SD 4096
#define KU 1280  // 5 * 256

__device__ __forceinline__ void gload16(const void* g, void* lds) {
  __builtin_amdgcn_global_load_lds(
      (const __attribute__((address_space(1))) unsigned int*)g,
      (__attribute__((address_space(3))) unsigned int*)lds, 16, 0, 0);
}

// ---------------- prep X (+ merged prep_w3): t2p, t5T, t6, A ----------------
__global__ __launch_bounds__(256) void prep_x(const float* __restrict__ x,
                                              const float* __restrict__ p2,
                                              const float* __restrict__ p4,
                                              const float* __restrict__ p6,
                                              const float* __restrict__ p3,
                                              __hip_bfloat16* __restrict__ t2p,
                                              __hip_bfloat16* __restrict__ t5T,
                                              __hip_bfloat16* __restrict__ t6,
                                              __hip_bfloat16* __restrict__ A) {
  int h = blockIdx.x;
  int cb = blockIdx.y;
  int n = blockIdx.z;
  int c0 = cb * 64;
  __shared__ float xwp[64][76];             // [c][4 pad | w 0..63 | 4 pad | 4 unused]
  __shared__ __hip_bfloat16 t5l[64][72];    // [w][c + 8 pad]
  __shared__ __hip_bfloat16 t2l[64][72];
  int t = threadIdx.x;

  // merged prep_w3: A[o][j*256+c] = p3[o,c,0,j]
  {
    int bid = (n * 64 + h) * 4 + cb;  // 0..4095
    int id = bid * 256 + t;
    if (id < CD * KU) {
      int o = id / KU;
      int r = id - o * KU;
      int j = r >> 8;
      int c = r & 255;
      A[id] = __float2bfloat16(p3[(o * CD + c) * 5 + j]);
    }
  }

  // zero xwp pads (cols 0..3 and 68..71)
  {
    int r = t >> 2, cc = t & 3;
    xwp[r][cc] = 0.f;
    xwp[r][68 + cc] = 0.f;
  }

  // phase 0: coalesced loads; lane already holds its output c-column
  {
    int w = t & 63, cg = (t >> 6) * 16;  // cg wave-uniform
    __hip_bfloat16 o5[16], o2[16];
#pragma unroll
    for (int j = 0; j < 16; ++j) {
      int c = c0 + cg + j;
      float xv = x[(((size_t)n * CD + c) * HD + h) * WD + w];
      float sc = p2[c * HD + h];  // wave-uniform address -> broadcast
      xwp[cg + j][4 + w] = xv;
      o5[j] = __float2bfloat16(fmaxf(xv, 0.f));
      o2[j] = __float2bfloat16(sc * xv);
    }
    *reinterpret_cast<bf16x8*>(&t5l[w][cg]) = *reinterpret_cast<const bf16x8*>(&o5[0]);
    *reinterpret_cast<bf16x8*>(&t5l[w][cg + 8]) = *reinterpret_cast<const bf16x8*>(&o5[8]);
    *reinterpret_cast<bf16x8*>(&t2l[w][cg]) = *reinterpret_cast<const bf16x8*>(&o2[0]);
    *reinterpret_cast<bf16x8*>(&t2l[w][cg + 8]) = *reinterpret_cast<const bf16x8*>(&o2[8]);
  }
  __syncthreads();

  __hip_bfloat16* t2pn = t2p + (size_t)n * HD * WP * CD;

  // phase 1: vectorized LDS reads -> coalesced global stores
  {
    int ws = t >> 2, ch = (t & 3) * 16;
    bf16x8 v0 = *reinterpret_cast<const bf16x8*>(&t5l[ws][ch]);
    bf16x8 v1 = *reinterpret_cast<const bf16x8*>(&t5l[ws][ch + 8]);
    size_t s = (size_t)h * 64 + ws;
    *reinterpret_cast<bf16x8*>(&t5T[((size_t)n * SD + s) * CD + c0 + ch]) = v0;
    *reinterpret_cast<bf16x8*>(&t5T[((size_t)n * SD + s) * CD + c0 + ch + 8]) = v1;
    bf16x8 u0 = *reinterpret_cast<const bf16x8*>(&t2l[ws][ch]);
    bf16x8 u1 = *reinterpret_cast<const bf16x8*>(&t2l[ws][ch + 8]);
    *reinterpret_cast<bf16x8*>(&t2pn[((size_t)h * WP + ws + 2) * CD + c0 + ch]) = u0;
    *reinterpret_cast<bf16x8*>(&t2pn[((size_t)h * WP + ws + 2) * CD + c0 + ch + 8]) = u1;
  }
  // zero pads: wp in {0,1,66,67}
  if (t < 32) {
    int pi = t >> 3;
    int wp = (pi < 2) ? pi : pi + 64;
    int cc = (t & 7) * 8;
    bf16x8 z = (bf16x8){0, 0, 0, 0, 0, 0, 0, 0};
    *reinterpret_cast<bf16x8*>(&t2pn[((size_t)h * WP + wp) * CD + c0 + cc]) = z;
  }

  // phase 2: t6 via aligned float4 halo reads, 16 outputs/thread
  {
    int cl = t >> 2, w16 = (t & 3) * 16;
    float hx[24];
#pragma unroll
    for (int q = 0; q < 6; ++q) {
      float4 v = *reinterpret_cast<const float4*>(&xwp[cl][w16 + q * 4]);
      hx[q * 4 + 0] = v.x;
      hx[q * 4 + 1] = v.y;
      hx[q * 4 + 2] = v.z;
      hx[q * 4 + 3] = v.w;
    }
    float wt[7];
#pragma unroll
    for (int k = 0; k < 7; ++k) wt[k] = p4[(c0 + cl) * 7 + k] * p6[k];  // quad-shared
    __hip_bfloat16 o6[16];
#pragma unroll
    for (int u = 0; u < 16; ++u) {
      float acc = 0.f;
#pragma unroll
      for (int k = 0; k < 7; ++k) acc += wt[k] * hx[u + 1 + k];
      o6[u] = __float2bfloat16(acc);
    }
    size_t base = ((size_t)n * CD + c0 + cl) * SD + h * 64 + w16;
    *reinterpret_cast<bf16x8*>(&t6[base]) = *reinterpret_cast<const bf16x8*>(&o6[0]);
    *reinterpret_cast<bf16x8*>(&t6[base + 8]) = *reinterpret_cast<const bf16x8*>(&o6[8]);
  }
}

// ---------------- GEMM B (TLP variant: 256x128 tile, BK=32, 2 LDS bufs = 48KB) ---------
// grid: (sb=32, 1, n=16) = 512 blocks = 2 resident/CU (capacity 3). 8 waves 4Mx2N,
// wave tile 64x64, 16 MFMA + 8 ds_read_b128 per tile. Depth-1 schedule per tile:
// {ST3(kt+1,nxt); LDF(cur); MM; VMWAIT(0); BAR} — the intra-block drain is covered
// by the co-resident block's MFMA phase (m114 TLP overlap).
// Swizzle identical to round-10: phys granule = log ^ ((row>>1)&3), both sides.
#define VMWAIT(N) asm volatile("s_waitcnt vmcnt(" #N ")" ::: "memory")
#define BARRIER() __builtin_amdgcn_s_barrier()

#define ST3(kt, bi)                                                                    \
  do {                                                                                 \
    char* dst = lb + (bi) * 24576 + t * 16;                                            \
    gload16(gA0 + (kt) * 64, dst);            /* A rows 0..127   */                    \
    gload16(gA1 + (kt) * 64, dst + 8192);     /* A rows 128..255 */                    \
    gload16(gB0 + (kt) * 64, dst + 16384);    /* B rows 0..127   */                    \
  } while (0)

#define LDF(bi, AV, BV)                                                                \
  do {                                                                                 \
    const char* ba = lb + (bi) * 24576;                                                \
    _Pragma("unroll") for (int mf = 0; mf < 4; ++mf) {                                 \
      int row = wm * 64 + mf * 16 + l16;                                               \
      AV[mf] = *reinterpret_cast<const bf16x8*>(ba + row * 64 + ((lg ^ rxor) * 16));   \
    }                                                                                  \
    _Pragma("unroll") for (int nf = 0; nf < 4; ++nf) {                                 \
      int row = wn * 64 + nf * 16 + l16;                                               \
      BV[nf] = *reinterpret_cast<const bf16x8*>(ba + 16384 + row * 64 +                \
                                                ((lg ^ rxor) * 16));                   \
    }                                                                                  \
  } while (0)

#define MM(AV, BV)                                                                     \
  do {                                                                                 \
    __builtin_amdgcn_s_setprio(1);                                                     \
    _Pragma("unroll") for (int mf = 0; mf < 4; ++mf)                                   \
        _Pragma("unroll") for (int nf = 0; nf < 4; ++nf)                               \
            acc[mf][nf] = __builtin_amdgcn_mfma_f32_16x16x32_bf16(AV[mf], BV[nf],      \
                                                                  acc[mf][nf], 0, 0, 0); \
    __builtin_amdgcn_s_setprio(0);                                                     \
  } while (0)

__global__ __launch_bounds__(512, 4) void gemm_b8(const __hip_bfloat16* __restrict__ A,
                                                  const __hip_bfloat16* __restrict__ t2p,
                                                  __hip_bfloat16* __restrict__ t3) {
  __shared__ __align__(16) __hip_bfloat16 lds[24576];  // 48 KiB = 2 x 24 KB
  char* lb = (char*)lds;
  const int n = blockIdx.z;
  const int sb = blockIdx.x;
  const int t = threadIdx.x;
  const int wv = t >> 6, lane = t & 63;
  const int wm = wv >> 1, wn = wv & 1;
  const int l16 = lane & 15, lg = lane >> 4;
  const int s0 = sb * 128;
  const int rxor = (l16 >> 1) & 3;
  const char* Ab = (const char*)A;
  const char* t2pb = (const char*)(t2p + (size_t)n * HD * WP * CD);
  const int cbsrc = ((t & 3) ^ ((t >> 3) & 3)) * 16;  // src-side granule swizzle

  const int r0 = t >> 2;  // 0..127
  const char* gA0 = Ab + (size_t)r0 * 2560 + cbsrc;
  const char* gA1 = Ab + (size_t)(r0 + 128) * 2560 + cbsrc;
  const int s1 = s0 + r0;
  const char* gB0 = t2pb + (size_t)(s1 + 4 * (s1 >> 6)) * 512 + cbsrc;

  f32x4 acc[4][4];
#pragma unroll
  for (int i = 0; i < 4; ++i)
#pragma unroll
    for (int j = 0; j < 4; ++j) acc[i][j] = (f32x4){0.f, 0.f, 0.f, 0.f};

  bf16x8 av[4], bv[4];

  ST3(0, 0);
  VMWAIT(0);
  BARRIER();

  for (int kt = 0; kt < 40; ++kt) {
    const int cur = kt & 1;
    if (kt < 39) ST3(kt + 1, cur ^ 1);
    LDF(cur, av, bv);
    MM(av, bv);
    if (kt < 39) {
      VMWAIT(0);
      BARRIER();
    }
  }

  __hip_bfloat16* t3n = t3 + (size_t)n * CD * SD;
#pragma unroll
  for (int mf = 0; mf < 4; ++mf)
#pragma unroll
    for (int nf = 0; nf < 4; ++nf) {
      int row0 = wm * 64 + mf * 16 + lg * 4;
      int col = s0 + wn * 64 + nf * 16 + l16;
#pragma unroll
      for (int r = 0; r < 4; ++r)
        t3n[(size_t)(row0 + r) * SD + col] = __float2bfloat16(acc[mf][nf][r]);
    }
}

// ---------------- GEMM C (K-split x4): P4[kc][n][d][c] = sum_{s in chunk} t6*t3 ---------
__global__ __launch_bounds__(256) void gemm_c_part(const __hip_bfloat16* __restrict__ t6,
                                                   const __hip_bfloat16* __restrict__ t3,
                                                   float* __restrict__ P4) {
  __shared__ __align__(16) __hip_bfloat16 lA[64 * 64];
  __shared__ __align__(16) __hip_bfloat16 lB[64 * 64];
  int bx = blockIdx.x;
  int cbk = bx & 3, kc = bx >> 2;
  int db = blockIdx.y;
  int n = blockIdx.z;
  int t = threadIdx.x;
  int wave = t >> 6, lane = t & 63;
  int wm = wave >> 1, wn = wave & 1;
  int l16 = lane & 15, lg = lane >> 4;
  int d0 = db * 64;
  int c0 = cbk * 64;
  int kbase = kc * 1024;
  const __hip_bfloat16* An = t6 + (size_t)n * CD * SD + kbase;
  const __hip_bfloat16* Bn = t3 + (size_t)n * CD * SD + kbase;

  int srow = t >> 3;
  int scol = (t & 7) * 8;
  const __hip_bfloat16* gA0 = An + (size_t)(d0 + srow) * SD + scol;
  const __hip_bfloat16* gA1 = An + (size_t)(d0 + srow + 32) * SD + scol;
  const __hip_bfloat16* gB0 = Bn + (size_t)(c0 + srow) * SD + scol;
  const __hip_bfloat16* gB1 = Bn + (size_t)(c0 + srow + 32) * SD + scol;
  __hip_bfloat16* lAd0 = &lA[t * 8];
  __hip_bfloat16* lAd1 = &lA[t * 8 + 32 * 64];
  __hip_bfloat16* lBd0 = &lB[t * 8];
  __hip_bfloat16* lBd1 = &lB[t * 8 + 32 * 64];

  f32x4 acc[2][2];
#pragma unroll
  for (int mi = 0; mi < 2; ++mi)
#pragma unroll
    for (int ni = 0; ni < 2; ++ni) acc[mi][ni] = (f32x4){0.f, 0.f, 0.f, 0.f};

  gload16(gA0, lAd0);
  gload16(gA1, lAd1);
  gload16(gB0, lBd0);
  gload16(gB1, lBd1);

  for (int k = 0; k < 16; ++k) {
    __syncthreads();
#pragma unroll
    for (int ks = 0; ks < 2; ++ks) {
      bf16x8 a[2], b[2];
#pragma unroll
      for (int mi = 0; mi < 2; ++mi)
        a[mi] = *reinterpret_cast<const bf16x8*>(&lA[(wm * 32 + mi * 16 + l16) * 64 + ks * 32 + lg * 8]);
#pragma unroll
      for (int ni = 0; ni < 2; ++ni)
        b[ni] = *reinterpret_cast<const bf16x8*>(&lB[(wn * 32 + ni * 16 + l16) * 64 + ks * 32 + lg * 8]);
#pragma unroll
      for (int mi = 0; mi < 2; ++mi)
#pragma unroll
        for (int ni = 0; ni < 2; ++ni)
          acc[mi][ni] = __builtin_amdgcn_mfma_f32_16x16x32_bf16(a[mi], b[ni], acc[mi][ni], 0, 0, 0);
    }
    __syncthreads();
    if (k < 15) {
      int kk = (k + 1) * 64;
      gload16(gA0 + kk, lAd0);
      gload16(gA1 + kk, lAd1);
      gload16(gB0 + kk, lBd0);
      gload16(gB1 + kk, lBd1);
    }
  }

  float* Pn = P4 + ((size_t)kc * NB + n) * CD * CD;
#pragma unroll
  for (int mi = 0; mi < 2; ++mi)
#pragma unroll
    for (int ni = 0; ni < 2; ++ni) {
      int col = c0 + wn * 32 + ni * 16 + l16;
      int row0 = d0 + wm * 32 + mi * 16 + lg * 4;
#pragma unroll
      for (int r = 0; r < 4; ++r)
        Pn[(size_t)(row0 + r) * CD + col] = acc[mi][ni][r];
    }
}

// ---------------- reduce P4 -> P (bf16, x 1/64) ----------------
__global__ __launch_bounds__(256) void reduce_P(const float* __restrict__ P4,
                                                __hip_bfloat16* __restrict__ P) {
  size_t i = ((size_t)blockIdx.x * 256 + threadIdx.x) * 4;
  const size_t stride = (size_t)NB * CD * CD;
  float4 a = *reinterpret_cast<const float4*>(P4 + i);
  float4 b = *reinterpret_cast<const float4*>(P4 + stride + i);
  float4 c = *reinterpret_cast<const float4*>(P4 + 2 * stride + i);
  float4 d = *reinterpret_cast<const float4*>(P4 + 3 * stride + i);
  __hip_bfloat16 o[4];
  o[0] = __float2bfloat16((a.x + b.x + c.x + d.x) * 0.015625f);
  o[1] = __float2bfloat16((a.y + b.y + c.y + d.y) * 0.015625f);
  o[2] = __float2bfloat16((a.z + b.z + c.z + d.z) * 0.015625f);
  o[3] = __float2bfloat16((a.w + b.w + c.w + d.w) * 0.015625f);
  *reinterpret_cast<short4*>(&P[i]) = *reinterpret_cast<const short4*>(o);
}

// ---------------- GEMM D: out[n][d][s] = (1/16) * sum_c P[n][d][c] * t5T[n][s][c] -------
#define DSTAGE_A(i, kk)                                                                \
  gload16(Pb + (size_t)((i) * 32 + wv4 * 8 + (lane >> 3)) * 512 + (kk) * 128 + cbsrc,  \
          (char*)lA + (i) * 4096 + wv4 * 1024)
#define DSTAGE_B(i, kk)                                                                \
  gload16(Tb + (size_t)(s0 + (i) * 32 + wv4 * 8 + (lane >> 3)) * 512 + (kk) * 128 + cbsrc, \
          (char*)lB + (i) * 4096 + wv4 * 1024)

__global__ __launch_bounds__(256, 2) void gemm_d(const __hip_bfloat16* __restrict__ P,
                                                 const __hip_bfloat16* __restrict__ t5T,
                                                 float* __restrict__ out) {
  __shared__ __align__(16) __hip_bfloat16 lA[256 * 64];  // 32 KB
  __shared__ __align__(16) __hip_bfloat16 lB[128 * 64];  // 16 KB
  const int n = blockIdx.z;
  const int sb = blockIdx.x;
  const int t = threadIdx.x;
  const int wv4 = t >> 6, lane = t & 63;
  const int wm = wv4 >> 1, wn = wv4 & 1;
  const int l16 = lane & 15, lg = lane >> 4;
  const int s0 = sb * 128;
  const char* Pb = (const char*)(P + (size_t)n * CD * CD);
  const char* Tb = (const char*)(t5T + (size_t)n * SD * CD);
  const int cbsrc = ((lane & 7) ^ (lane >> 3)) * 16;
  const int lxor = (l16 & 7) * 8;

  f32x4 acc[8][4];
#pragma unroll
  for (int i = 0; i < 8; ++i)
#pragma unroll
    for (int j = 0; j < 4; ++j) acc[i][j] = (f32x4){0.f, 0.f, 0.f, 0.f};

#pragma unroll
  for (int i = 0; i < 8; ++i) DSTAGE_A(i, 0);
#pragma unroll
  for (int i = 0; i < 4; ++i) DSTAGE_B(i, 0);

  for (int k = 0; k < 4; ++k) {
    __syncthreads();
#pragma unroll
    for (int ks = 0; ks < 2; ++ks) {
      int cb = (ks * 32 + lg * 8) ^ lxor;
      bf16x8 a[8], b[4];
#pragma unroll
      for (int mf = 0; mf < 8; ++mf)
        a[mf] = *reinterpret_cast<const bf16x8*>(&lA[(wm * 128 + mf * 16 + l16) * 64 + cb]);
#pragma unroll
      for (int nf = 0; nf < 4; ++nf)
        b[nf] = *reinterpret_cast<const bf16x8*>(&lB[(wn * 64 + nf * 16 + l16) * 64 + cb]);
#pragma unroll
      for (int mf = 0; mf < 8; ++mf)
#pragma unroll
        for (int nf = 0; nf < 4; ++nf)
          acc[mf][nf] = __builtin_amdgcn_mfma_f32_16x16x32_bf16(a[mf], b[nf], acc[mf][nf], 0, 0, 0);
    }
    __syncthreads();
    if (k < 3) {
      int kk = k + 1;
#pragma unroll
      for (int i = 0; i < 8; ++i) DSTAGE_A(i, kk);
#pragma unroll
      for (int i = 0; i < 4; ++i) DSTAGE_B(i, kk);
    }
  }

  float* outn = out + (size_t)n * CD * SD;
#pragma unroll
  for (int mf = 0; mf < 8; ++mf)
#pragma unroll
    for (int nf = 0; nf < 4; ++nf) {
      int col = s0 + wn * 64 + nf * 16 + l16;
      int row0 = wm * 128 + mf * 16 + lg * 4;
#pragma unroll
      for (int r = 0; r < 4; ++r)
        outn[(size_t)(row0 + r) * SD + col] = acc[mf][nf][r] * 0.0625f;
    }
}

extern "C" void kernel_launch(void* const* d_in, const int* in_sizes, int n_in,
                              void* d_out, int out_size, void* d_ws, size_t ws_size,
                              hipStream_t stream) {
  const float* x = (const float*)d_in[0];
  const float* p2 = (const float*)d_in[1];
  const float* p3 = (const float*)d_in[2];
  const float* p4 = (const float*)d_in[3];
  const float* p6 = (const float*)d_in[4];

  char* ws = (char*)d_ws;
  size_t off = 0;
  __hip_bfloat16* A = (__hip_bfloat16*)(ws + off);
  off += (size_t)CD * KU * 2;                       // 640 KiB
  size_t t2p_off = off;
  __hip_bfloat16* t2p = (__hip_bfloat16*)(ws + off);
  off += (size_t)NB * HD * WP * CD * 2;             // ~35.7 MiB
  __hip_bfloat16* t5T = (__hip_bfloat16*)(ws + off);
  off += (size_t)NB * SD * CD * 2;                  // 32 MiB
  __hip_bfloat16* t6 = (__hip_bfloat16*)(ws + off);
  off += (size_t)NB * CD * SD * 2;                  // 32 MiB
  __hip_bfloat16* t3 = (__hip_bfloat16*)(ws + off);
  off += (size_t)NB * CD * SD * 2;                  // 32 MiB
  float* P4 = (float*)(ws + t2p_off);
  __hip_bfloat16* P = (__hip_bfloat16*)(ws + t2p_off + (size_t)4 * NB * CD * CD * 4);

  float* out = (float*)d_out;

  prep_x<<<dim3(HD, 4, NB), 256, 0, stream>>>(x, p2, p4, p6, p3, t2p, t5T, t6, A);
  gemm_b8<<<dim3(32, 1, NB), 512, 0, stream>>>(A, t2p, t3);
  gemm_c_part<<<dim3(16, 4, NB), 256, 0, stream>>>(t6, t3, P4);
  reduce_P<<<dim3((NB * CD * CD / 4) / 256), 256, 0, stream>>>(P4, P);
  gemm_d<<<dim3(32, 1, NB), 256, 0, stream>>>(P, t5T, out);
}

// Round 17
// 128.673 us; speedup vs baseline: 1.0506x; 1.0506x over previous
//
#include <hip/hip_runtime.h>
#include <hip/hip_bf16.h>

typedef __attribute__((ext_vector_type(8))) short bf16x8;
typedef __attribute__((ext_vector_type(4))) float f32x4;

#define NB 16
#define CD 256
#define HD 64
#define WD 64
#define WP 68   // padded width
#define SD 4096
#define KU 1280  // 5 * 256

__device__ __forceinline__ void gload16(const void* g, void* lds) {
  __builtin_amdgcn_global_load_lds(
      (const __attribute__((address_space(1))) unsigned int*)g,
      (__attribute__((address_space(3))) unsigned int*)lds, 16, 0, 0);
}

// ---------------- prep X (+ merged prep_w3): t2p, t5T, t6, A ----------------
__global__ __launch_bounds__(256) void prep_x(const float* __restrict__ x,
                                              const float* __restrict__ p2,
                                              const float* __restrict__ p4,
                                              const float* __restrict__ p6,
                                              const float* __restrict__ p3,
                                              __hip_bfloat16* __restrict__ t2p,
                                              __hip_bfloat16* __restrict__ t5T,
                                              __hip_bfloat16* __restrict__ t6,
                                              __hip_bfloat16* __restrict__ A) {
  int h = blockIdx.x;
  int c0 = blockIdx.y * 64;
  int n = blockIdx.z;
  __shared__ float xl[64][67];
  __shared__ float p2l[64];
  __shared__ float wtl[64][8];
  int t = threadIdx.x;

  // merged prep_w3: A[o][j*256+c] = p3[o,c,0,j]
  {
    int bid = (n * 64 + h) * 4 + blockIdx.y;  // 0..4095
    int id = bid * 256 + t;
    if (id < CD * KU) {
      int o = id / KU;
      int r = id - o * KU;
      int j = r >> 8;
      int c = r & 255;
      A[id] = __float2bfloat16(p3[(o * CD + c) * 5 + j]);
    }
  }

  if (t < 64) p2l[t] = p2[(c0 + t) * HD + h];
  for (int idx = t; idx < 448; idx += 256) {
    int c = idx / 7, k = idx - c * 7;
    wtl[c][k] = p4[(c0 + c) * 7 + k] * p6[k];
  }

  {
    int cq = t >> 4;
    int w4 = (t & 15) * 4;
#pragma unroll
    for (int cc = 0; cc < 4; ++cc) {
      int cl = cc * 16 + cq;
      const float4 xv = *reinterpret_cast<const float4*>(
          &x[(((size_t)n * CD + c0 + cl) * HD + h) * WD + w4]);
      xl[cl][w4 + 0] = xv.x;
      xl[cl][w4 + 1] = xv.y;
      xl[cl][w4 + 2] = xv.z;
      xl[cl][w4 + 3] = xv.w;
    }
  }
  __syncthreads();

  __hip_bfloat16* t2pn = t2p + (size_t)n * HD * WP * CD;
#pragma unroll
  for (int ii = 0; ii < 2; ++ii) {
    int w = (t >> 3) + ii * 32;
    int cb = (t & 7) * 8;
    __hip_bfloat16 o2[8], o5[8];
#pragma unroll
    for (int j = 0; j < 8; ++j) {
      float xv = xl[cb + j][w];
      o5[j] = __float2bfloat16(fmaxf(xv, 0.f));
      o2[j] = __float2bfloat16(p2l[cb + j] * xv);
    }
    size_t s = (size_t)h * 64 + w;
    *reinterpret_cast<bf16x8*>(&t5T[((size_t)n * SD + s) * CD + c0 + cb]) =
        *reinterpret_cast<const bf16x8*>(o5);
    *reinterpret_cast<bf16x8*>(&t2pn[((size_t)h * WP + w + 2) * CD + c0 + cb]) =
        *reinterpret_cast<const bf16x8*>(o2);
  }
  if (t < 32) {
    int pi = t >> 3;
    int wp = (pi < 2) ? pi : pi + 64;
    int cb = (t & 7) * 8;
    bf16x8 z = (bf16x8){0, 0, 0, 0, 0, 0, 0, 0};
    *reinterpret_cast<bf16x8*>(&t2pn[((size_t)h * WP + wp) * CD + c0 + cb]) = z;
  }

#pragma unroll
  for (int ii = 0; ii < 2; ++ii) {
    int cl = (t >> 3) + ii * 32;
    int w8 = (t & 7) * 8;
    float hx[14];
#pragma unroll
    for (int m = 0; m < 14; ++m) {
      int wi = w8 - 3 + m;
      hx[m] = (wi >= 0 && wi < 64) ? xl[cl][wi] : 0.f;
    }
    float wt[7];
#pragma unroll
    for (int k = 0; k < 7; ++k) wt[k] = wtl[cl][k];
    __hip_bfloat16 o6[8];
#pragma unroll
    for (int u = 0; u < 8; ++u) {
      float acc = 0.f;
#pragma unroll
      for (int k = 0; k < 7; ++k) acc += wt[k] * hx[u + k];
      o6[u] = __float2bfloat16(acc);
    }
    *reinterpret_cast<bf16x8*>(&t6[((size_t)n * CD + c0 + cl) * SD + h * 64 + w8]) =
        *reinterpret_cast<const bf16x8*>(o6);
  }
}

// ---------------- GEMM B (depth-2 pipeline, 256x256 tile, BK=32, 4 LDS bufs) -----------
// Best-measured schedule (44.3 us): per tile {ST4(kt+2); MM(kt); VMWAIT(4); BARRIER;
// LDF(kt+1)}. Counted vmcnt never 0 in steady state; fragments register-double-buffered.
#define VMWAIT(N) asm volatile("s_waitcnt vmcnt(" #N ")" ::: "memory")
#define BARRIER() __builtin_amdgcn_s_barrier()

#define ST4(kt, bi)                                                                    \
  do {                                                                                 \
    char* dst = lb + ((bi) << 15) + t * 16;                                            \
    gload16(gA0 + (kt) * 64, dst);                                                     \
    gload16(gA1 + (kt) * 64, dst + 8192);                                              \
    gload16(gB0 + (kt) * 64, dst + 16384);                                             \
    gload16(gB1 + (kt) * 64, dst + 24576);                                             \
  } while (0)

#define LDF(bi, AV, BV)                                                                \
  do {                                                                                 \
    const char* ba = lb + ((bi) << 15);                                                \
    _Pragma("unroll") for (int mf = 0; mf < 8; ++mf) {                                 \
      int row = wm * 128 + mf * 16 + l16;                                              \
      AV[mf] = *reinterpret_cast<const bf16x8*>(ba + row * 64 + ((lg ^ rxor) * 16));   \
    }                                                                                  \
    _Pragma("unroll") for (int nf = 0; nf < 4; ++nf) {                                 \
      int row = wn * 64 + nf * 16 + l16;                                               \
      BV[nf] = *reinterpret_cast<const bf16x8*>(ba + 16384 + row * 64 +                \
                                                ((lg ^ rxor) * 16));                   \
    }                                                                                  \
  } while (0)

#define MM(AV, BV)                                                                     \
  do {                                                                                 \
    __builtin_amdgcn_s_setprio(1);                                                     \
    _Pragma("unroll") for (int mf = 0; mf < 8; ++mf)                                   \
        _Pragma("unroll") for (int nf = 0; nf < 4; ++nf)                               \
            acc[mf][nf] = __builtin_amdgcn_mfma_f32_16x16x32_bf16(AV[mf], BV[nf],      \
                                                                  acc[mf][nf], 0, 0, 0); \
    __builtin_amdgcn_s_setprio(0);                                                     \
  } while (0)

__global__ __launch_bounds__(512, 2) void gemm_b8(const __hip_bfloat16* __restrict__ A,
                                                  const __hip_bfloat16* __restrict__ t2p,
                                                  __hip_bfloat16* __restrict__ t3) {
  __shared__ __align__(16) __hip_bfloat16 lds[65536];  // 128 KiB = 4 x 32 KB
  char* lb = (char*)lds;
  const int n = blockIdx.z;
  const int sb = blockIdx.x;
  const int t = threadIdx.x;
  const int wv = t >> 6, lane = t & 63;
  const int wm = wv >> 2, wn = wv & 3;
  const int l16 = lane & 15, lg = lane >> 4;
  const int s0 = sb * 256;
  const int rxor = (l16 >> 1) & 3;
  const char* Ab = (const char*)A;
  const char* t2pb = (const char*)(t2p + (size_t)n * HD * WP * CD);
  const int cbsrc = ((t & 3) ^ ((t >> 3) & 3)) * 16;  // src-side granule swizzle

  const int r0 = t >> 2;
  const char* gA0 = Ab + (size_t)r0 * 2560 + cbsrc;
  const char* gA1 = Ab + (size_t)(r0 + 128) * 2560 + cbsrc;
  const int s1 = s0 + r0, s2 = s0 + r0 + 128;
  const char* gB0 = t2pb + (size_t)(s1 + 4 * (s1 >> 6)) * 512 + cbsrc;
  const char* gB1 = t2pb + (size_t)(s2 + 4 * (s2 >> 6)) * 512 + cbsrc;

  f32x4 acc[8][4];
#pragma unroll
  for (int i = 0; i < 8; ++i)
#pragma unroll
    for (int j = 0; j < 4; ++j) acc[i][j] = (f32x4){0.f, 0.f, 0.f, 0.f};

  bf16x8 avX[8], bvX[4], avY[8], bvY[4];

  ST4(0, 0);
  ST4(1, 1);
  VMWAIT(4);
  BARRIER();
  LDF(0, avX, bvX);

  for (int k2 = 0; k2 < 18; ++k2) {
    const int kt = k2 * 2;
    ST4(kt + 2, (kt + 2) & 3);
    MM(avX, bvX);
    VMWAIT(4);
    BARRIER();
    LDF((kt + 1) & 3, avY, bvY);
    ST4(kt + 3, (kt + 3) & 3);
    MM(avY, bvY);
    VMWAIT(4);
    BARRIER();
    LDF((kt + 2) & 3, avX, bvX);
  }
  ST4(38, 2);
  MM(avX, bvX);
  VMWAIT(4);
  BARRIER();
  LDF(1, avY, bvY);
  ST4(39, 3);
  MM(avY, bvY);
  VMWAIT(4);
  BARRIER();
  LDF(2, avX, bvX);
  MM(avX, bvX);
  VMWAIT(0);
  BARRIER();
  LDF(3, avY, bvY);
  MM(avY, bvY);

  __hip_bfloat16* t3n = t3 + (size_t)n * CD * SD;
#pragma unroll
  for (int im = 0; im < 8; ++im)
#pragma unroll
    for (int in = 0; in < 4; ++in) {
      int row0 = wm * 128 + im * 16 + lg * 4;
      int col = s0 + wn * 64 + in * 16 + l16;
#pragma unroll
      for (int r = 0; r < 4; ++r)
        t3n[(size_t)(row0 + r) * SD + col] = __float2bfloat16(acc[im][in][r]);
    }
}

// ---------------- GEMM C (K-split x4): P4[kc][n][d][c] = sum_{s in chunk} t6*t3 ---------
__global__ __launch_bounds__(256) void gemm_c_part(const __hip_bfloat16* __restrict__ t6,
                                                   const __hip_bfloat16* __restrict__ t3,
                                                   float* __restrict__ P4) {
  __shared__ __align__(16) __hip_bfloat16 lA[64 * 64];
  __shared__ __align__(16) __hip_bfloat16 lB[64 * 64];
  int bx = blockIdx.x;
  int cbk = bx & 3, kc = bx >> 2;
  int db = blockIdx.y;
  int n = blockIdx.z;
  int t = threadIdx.x;
  int wave = t >> 6, lane = t & 63;
  int wm = wave >> 1, wn = wave & 1;
  int l16 = lane & 15, lg = lane >> 4;
  int d0 = db * 64;
  int c0 = cbk * 64;
  int kbase = kc * 1024;
  const __hip_bfloat16* An = t6 + (size_t)n * CD * SD + kbase;
  const __hip_bfloat16* Bn = t3 + (size_t)n * CD * SD + kbase;

  int srow = t >> 3;
  int scol = (t & 7) * 8;
  const __hip_bfloat16* gA0 = An + (size_t)(d0 + srow) * SD + scol;
  const __hip_bfloat16* gA1 = An + (size_t)(d0 + srow + 32) * SD + scol;
  const __hip_bfloat16* gB0 = Bn + (size_t)(c0 + srow) * SD + scol;
  const __hip_bfloat16* gB1 = Bn + (size_t)(c0 + srow + 32) * SD + scol;
  __hip_bfloat16* lAd0 = &lA[t * 8];
  __hip_bfloat16* lAd1 = &lA[t * 8 + 32 * 64];
  __hip_bfloat16* lBd0 = &lB[t * 8];
  __hip_bfloat16* lBd1 = &lB[t * 8 + 32 * 64];

  f32x4 acc[2][2];
#pragma unroll
  for (int mi = 0; mi < 2; ++mi)
#pragma unroll
    for (int ni = 0; ni < 2; ++ni) acc[mi][ni] = (f32x4){0.f, 0.f, 0.f, 0.f};

  gload16(gA0, lAd0);
  gload16(gA1, lAd1);
  gload16(gB0, lBd0);
  gload16(gB1, lBd1);

  for (int k = 0; k < 16; ++k) {
    __syncthreads();
#pragma unroll
    for (int ks = 0; ks < 2; ++ks) {
      bf16x8 a[2], b[2];
#pragma unroll
      for (int mi = 0; mi < 2; ++mi)
        a[mi] = *reinterpret_cast<const bf16x8*>(&lA[(wm * 32 + mi * 16 + l16) * 64 + ks * 32 + lg * 8]);
#pragma unroll
      for (int ni = 0; ni < 2; ++ni)
        b[ni] = *reinterpret_cast<const bf16x8*>(&lB[(wn * 32 + ni * 16 + l16) * 64 + ks * 32 + lg * 8]);
#pragma unroll
      for (int mi = 0; mi < 2; ++mi)
#pragma unroll
        for (int ni = 0; ni < 2; ++ni)
          acc[mi][ni] = __builtin_amdgcn_mfma_f32_16x16x32_bf16(a[mi], b[ni], acc[mi][ni], 0, 0, 0);
    }
    __syncthreads();
    if (k < 15) {
      int kk = (k + 1) * 64;
      gload16(gA0 + kk, lAd0);
      gload16(gA1 + kk, lAd1);
      gload16(gB0 + kk, lBd0);
      gload16(gB1 + kk, lBd1);
    }
  }

  float* Pn = P4 + ((size_t)kc * NB + n) * CD * CD;
#pragma unroll
  for (int mi = 0; mi < 2; ++mi)
#pragma unroll
    for (int ni = 0; ni < 2; ++ni) {
      int col = c0 + wn * 32 + ni * 16 + l16;
      int row0 = d0 + wm * 32 + mi * 16 + lg * 4;
#pragma unroll
      for (int r = 0; r < 4; ++r)
        Pn[(size_t)(row0 + r) * CD + col] = acc[mi][ni][r];
    }
}

// ---------------- reduce P4 -> P (bf16, x 1/64) ----------------
__global__ __launch_bounds__(256) void reduce_P(const float* __restrict__ P4,
                                                __hip_bfloat16* __restrict__ P) {
  size_t i = ((size_t)blockIdx.x * 256 + threadIdx.x) * 4;
  const size_t stride = (size_t)NB * CD * CD;
  float4 a = *reinterpret_cast<const float4*>(P4 + i);
  float4 b = *reinterpret_cast<const float4*>(P4 + stride + i);
  float4 c = *reinterpret_cast<const float4*>(P4 + 2 * stride + i);
  float4 d = *reinterpret_cast<const float4*>(P4 + 3 * stride + i);
  __hip_bfloat16 o[4];
  o[0] = __float2bfloat16((a.x + b.x + c.x + d.x) * 0.015625f);
  o[1] = __float2bfloat16((a.y + b.y + c.y + d.y) * 0.015625f);
  o[2] = __float2bfloat16((a.z + b.z + c.z + d.z) * 0.015625f);
  o[3] = __float2bfloat16((a.w + b.w + c.w + d.w) * 0.015625f);
  *reinterpret_cast<short4*>(&P[i]) = *reinterpret_cast<const short4*>(o);
}

// ---------------- GEMM D: out[n][d][s] = (1/16) * sum_c P[n][d][c] * t5T[n][s][c] -------
#define DSTAGE_A(i, kk)                                                                \
  gload16(Pb + (size_t)((i) * 32 + wv4 * 8 + (lane >> 3)) * 512 + (kk) * 128 + cbsrc,  \
          (char*)lA + (i) * 4096 + wv4 * 1024)
#define DSTAGE_B(i, kk)                                                                \
  gload16(Tb + (size_t)(s0 + (i) * 32 + wv4 * 8 + (lane >> 3)) * 512 + (kk) * 128 + cbsrc, \
          (char*)lB + (i) * 4096 + wv4 * 1024)

__global__ __launch_bounds__(256, 2) void gemm_d(const __hip_bfloat16* __restrict__ P,
                                                 const __hip_bfloat16* __restrict__ t5T,
                                                 float* __restrict__ out) {
  __shared__ __align__(16) __hip_bfloat16 lA[256 * 64];  // 32 KB
  __shared__ __align__(16) __hip_bfloat16 lB[128 * 64];  // 16 KB
  const int n = blockIdx.z;
  const int sb = blockIdx.x;
  const int t = threadIdx.x;
  const int wv4 = t >> 6, lane = t & 63;
  const int wm = wv4 >> 1, wn = wv4 & 1;
  const int l16 = lane & 15, lg = lane >> 4;
  const int s0 = sb * 128;
  const char* Pb = (const char*)(P + (size_t)n * CD * CD);
  const char* Tb = (const char*)(t5T + (size_t)n * SD * CD);
  const int cbsrc = ((lane & 7) ^ (lane >> 3)) * 16;
  const int lxor = (l16 & 7) * 8;

  f32x4 acc[8][4];
#pragma unroll
  for (int i = 0; i < 8; ++i)
#pragma unroll
    for (int j = 0; j < 4; ++j) acc[i][j] = (f32x4){0.f, 0.f, 0.f, 0.f};

#pragma unroll
  for (int i = 0; i < 8; ++i) DSTAGE_A(i, 0);
#pragma unroll
  for (int i = 0; i < 4; ++i) DSTAGE_B(i, 0);

  for (int k = 0; k < 4; ++k) {
    __syncthreads();
#pragma unroll
    for (int ks = 0; ks < 2; ++ks) {
      int cb = (ks * 32 + lg * 8) ^ lxor;
      bf16x8 a[8], b[4];
#pragma unroll
      for (int mf = 0; mf < 8; ++mf)
        a[mf] = *reinterpret_cast<const bf16x8*>(&lA[(wm * 128 + mf * 16 + l16) * 64 + cb]);
#pragma unroll
      for (int nf = 0; nf < 4; ++nf)
        b[nf] = *reinterpret_cast<const bf16x8*>(&lB[(wn * 64 + nf * 16 + l16) * 64 + cb]);
#pragma unroll
      for (int mf = 0; mf < 8; ++mf)
#pragma unroll
        for (int nf = 0; nf < 4; ++nf)
          acc[mf][nf] = __builtin_amdgcn_mfma_f32_16x16x32_bf16(a[mf], b[nf], acc[mf][nf], 0, 0, 0);
    }
    __syncthreads();
    if (k < 3) {
      int kk = k + 1;
#pragma unroll
      for (int i = 0; i < 8; ++i) DSTAGE_A(i, kk);
#pragma unroll
      for (int i = 0; i < 4; ++i) DSTAGE_B(i, kk);
    }
  }

  float* outn = out + (size_t)n * CD * SD;
#pragma unroll
  for (int mf = 0; mf < 8; ++mf)
#pragma unroll
    for (int nf = 0; nf < 4; ++nf) {
      int col = s0 + wn * 64 + nf * 16 + l16;
      int row0 = wm * 128 + mf * 16 + lg * 4;
#pragma unroll
      for (int r = 0; r < 4; ++r)
        outn[(size_t)(row0 + r) * SD + col] = acc[mf][nf][r] * 0.0625f;
    }
}

extern "C" void kernel_launch(void* const* d_in, const int* in_sizes, int n_in,
                              void* d_out, int out_size, void* d_ws, size_t ws_size,
                              hipStream_t stream) {
  const float* x = (const float*)d_in[0];
  const float* p2 = (const float*)d_in[1];
  const float* p3 = (const float*)d_in[2];
  const float* p4 = (const float*)d_in[3];
  const float* p6 = (const float*)d_in[4];

  char* ws = (char*)d_ws;
  size_t off = 0;
  __hip_bfloat16* A = (__hip_bfloat16*)(ws + off);
  off += (size_t)CD * KU * 2;                       // 640 KiB
  size_t t2p_off = off;
  __hip_bfloat16* t2p = (__hip_bfloat16*)(ws + off);
  off += (size_t)NB * HD * WP * CD * 2;             // ~35.7 MiB
  __hip_bfloat16* t5T = (__hip_bfloat16*)(ws + off);
  off += (size_t)NB * SD * CD * 2;                  // 32 MiB
  __hip_bfloat16* t6 = (__hip_bfloat16*)(ws + off);
  off += (size_t)NB * CD * SD * 2;                  // 32 MiB
  __hip_bfloat16* t3 = (__hip_bfloat16*)(ws + off);
  off += (size_t)NB * CD * SD * 2;                  // 32 MiB
  float* P4 = (float*)(ws + t2p_off);
  __hip_bfloat16* P = (__hip_bfloat16*)(ws + t2p_off + (size_t)4 * NB * CD * CD * 4);

  float* out = (float*)d_out;

  prep_x<<<dim3(HD, 4, NB), 256, 0, stream>>>(x, p2, p4, p6, p3, t2p, t5T, t6, A);
  gemm_b8<<<dim3(16, 1, NB), 512, 0, stream>>>(A, t2p, t3);
  gemm_c_part<<<dim3(16, 4, NB), 256, 0, stream>>>(t6, t3, P4);
  reduce_P<<<dim3((NB * CD * CD / 4) / 256), 256, 0, stream>>>(P4, P);
  gemm_d<<<dim3(32, 1, NB), 256, 0, stream>>>(P, t5T, out);
}